// Round 16
// baseline (1170.190 us; speedup 1.0000x reference)
//
#include <hip/hip_runtime.h>
#include <hip/hip_bf16.h>
#include <stdint.h>

// B=16, C=512, H=W=64, nh=16, hd=32, ws=8, shift=4, N=64 tok/window, Bw=1024,
// hid=2048. Softmax over HEAD axis (faithful bug) -> mask cancels; logits <= 26.
// QK row-norm (+ logits scale) folded into qkv GEMM epilogue (EPI=2).
// GEMM v8: 256x256 tile, 8 waves, fine 4-phase/K-tile schedule; A+B in LDS
// (2 x 64KB K-tile dbuf); one half-tile staged per phase; vmcnt(0) at group end.
//
// Workspace map (bytes), REQUIRES ws_size >= 411,041,792 (392 MiB):
//   [0        ,14400    ) btab f32 [16][225]
//   [16384    ,1589248  ) wbq bf16 [1536][512]
//   [1589248  ,2113536  ) wbo bf16 [512][512]
//   [2113536  ,4210688  ) wb1 bf16 [2048][512]
//   [4210688  ,6307840  ) wb2 bf16 [512][2048]
//   [8388608  ,75497472 ) x_temp bf16 NCHW          (dead after ln1; reused by h2)
//   [75497472 ,142606336) xw bf16 [65536][512]      (dead after qkv gemm; reused by o4, then h2)
//   [142606336,343932928) qkv bf16 [65536][1536]    (dead after attn; head reused by x2h, tail by h1)
//   [343932928,411041792) o_ws bf16 [65536][512]    (dead after out gemm; reused by y)

typedef float f32x4 __attribute__((ext_vector_type(4)));
typedef short s16x8 __attribute__((ext_vector_type(8)));

__device__ __forceinline__ float b2f(short u) {
  return __uint_as_float(((unsigned)(unsigned short)u) << 16);
}
__device__ __forceinline__ short f2b(float f) {
  __hip_bfloat16 h = __float2bfloat16(f);
  short s;
  __builtin_memcpy(&s, &h, 2);
  return s;
}
__device__ __forceinline__ void gload16(const void* g, void* l) {
  __builtin_amdgcn_global_load_lds((const unsigned int*)g, (unsigned int*)l, 16, 0, 0);
}

// ---------------- fp32 -> bf16 weight conversion (all 4 weights, one launch) ----------------
__global__ __launch_bounds__(256) void k_f2b4(const float* __restrict__ s0, short* __restrict__ d0,
                                              const float* __restrict__ s1, short* __restrict__ d1,
                                              const float* __restrict__ s2, short* __restrict__ d2,
                                              const float* __restrict__ s3, short* __restrict__ d3) {
  int b = blockIdx.x;
  const float* s;
  short* d;
  int base;
  if (b < 768) { s = s0; d = d0; base = b * 1024; }
  else if (b < 1024) { s = s1; d = d1; base = (b - 768) * 1024; }
  else if (b < 2048) { s = s2; d = d2; base = (b - 1024) * 1024; }
  else { s = s3; d = d3; base = (b - 2048) * 1024; }
  int i = base + threadIdx.x * 4;
  f32x4 v = *(const f32x4*)&s[i];
  ushort4 o;
  o.x = (unsigned short)f2b(v[0]);
  o.y = (unsigned short)f2b(v[1]);
  o.z = (unsigned short)f2b(v[2]);
  o.w = (unsigned short)f2b(v[3]);
  *(ushort4*)&d[i] = o;
}

// ---------------- CPB bias table ----------------
__global__ __launch_bounds__(64) void k_cpb(const float* __restrict__ w1,
                                            const float* __restrict__ w2,
                                            float* __restrict__ btab) {
  const int r = blockIdx.x;
  const int lane = threadIdx.x;
  const int ri = r / 15, rj = r % 15;
  float th = (float)(ri - 7) * (8.f / 7.f);
  float tw = (float)(rj - 7) * (8.f / 7.f);
  float gh = copysignf(log2f(fabsf(th) + 1.f) * (1.f / 3.f), th);
  float gw = copysignf(log2f(fabsf(tw) + 1.f) * (1.f / 3.f), tw);
  const int h = lane >> 2, pp = lane & 3;
  float acc = 0.f;
  for (int k = 0; k < 128; ++k) {
    int hh = pp * 128 + k;
    float a = gh * w1[hh * 2] + gw * w1[hh * 2 + 1];
    float r6 = fminf(fmaxf(a + 3.f, 0.f), 6.f);
    float hsw = a * r6 * (1.f / 6.f);
    acc += hsw * w2[h * 512 + hh];
  }
  acc += __shfl_xor(acc, 1);
  acc += __shfl_xor(acc, 2);
  if ((lane & 3) == 0) btab[h * 225 + r] = 16.f / (1.f + __expf(-acc));
}

// ---------------- LPU: x + depthwise 3x3 (SAME), out bf16 NCHW ----------------
__global__ __launch_bounds__(256) void k_lpu(const float* __restrict__ x,
                                             const float* __restrict__ lw,
                                             short* __restrict__ xt) {
  __shared__ float img[64 * 68];
  const int bc = blockIdx.x;
  const int c = bc & 511;
  const float* img_g = x + (size_t)bc * 4096;
  short* outp = xt + (size_t)bc * 4096;
  const int tid = threadIdx.x;
#pragma unroll
  for (int t = 0; t < 4; ++t) {
    int idx = t * 256 + tid;
    int h = idx >> 4, w4 = (idx & 15) * 4;
    f32x4 v = *(const f32x4*)&img_g[h * 64 + w4];
    *(f32x4*)&img[h * 68 + w4] = v;
  }
  float wreg[9];
#pragma unroll
  for (int t = 0; t < 9; ++t) wreg[t] = lw[c * 9 + t];
  __syncthreads();
  const int hb = tid >> 4, w0 = (tid & 15) * 4;
#pragma unroll
  for (int g = 0; g < 4; ++g) {
    int h = hb + g * 16;
    float row[3][6];
#pragma unroll
    for (int dr = 0; dr < 3; ++dr) {
      int hh = h - 1 + dr;
      if (hh < 0 || hh > 63) {
#pragma unroll
        for (int j = 0; j < 6; ++j) row[dr][j] = 0.f;
      } else {
        f32x4 m = *(const f32x4*)&img[hh * 68 + w0];
        row[dr][1] = m[0]; row[dr][2] = m[1]; row[dr][3] = m[2]; row[dr][4] = m[3];
        row[dr][0] = (w0 > 0) ? img[hh * 68 + w0 - 1] : 0.f;
        row[dr][5] = (w0 < 60) ? img[hh * 68 + w0 + 4] : 0.f;
      }
    }
    ushort4 o;
    unsigned short op[4];
#pragma unroll
    for (int p = 0; p < 4; ++p) {
      float acc = row[1][p + 1];
#pragma unroll
      for (int dr = 0; dr < 3; ++dr)
#pragma unroll
        for (int dc = 0; dc < 3; ++dc)
          acc += wreg[dr * 3 + dc] * row[dr][p + dc];
      op[p] = (unsigned short)f2b(acc);
    }
    o.x = op[0]; o.y = op[1]; o.z = op[2]; o.w = op[3];
    *(ushort4*)&outp[h * 64 + w0] = o;
  }
}

// ---------------- roll(-4,-4) over (tokens,channels) + window partition ----------------
__global__ __launch_bounds__(256) void k_xpose(const short* __restrict__ xt,
                                               short* __restrict__ xw) {
  __shared__ short tile[64][132];
  const int tid = threadIdx.x;
  const int cq = blockIdx.x & 3;
  const int h = (blockIdx.x >> 2) & 63;
  const int b = blockIdx.x >> 8;
  const int c0 = cq * 128;
  for (int idx = tid; idx < 64 * 128; idx += 256) {
    int ww = idx & 63, cc = idx >> 6;
    int csrc = (c0 + cc + 4) & 511;
    tile[ww][cc] = xt[(((size_t)b * 512 + csrc) * 64 + h) * 64 + ww];
  }
  __syncthreads();
  for (int qd = tid; qd < 64 * 32; qd += 256) {
    int ws_ = qd >> 5, cqq = qd & 31, cc = cqq * 4;
    int t = (h * 64 + ws_ + 4092) & 4095;
    int hd = t >> 6, wd = t & 63;
    int tok = (b * 64 + (hd >> 3) * 8 + (wd >> 3)) * 64 + (hd & 7) * 8 + (wd & 7);
    ushort4 u = *(const ushort4*)&tile[ws_][cc];
    *(ushort4*)&xw[(size_t)tok * 512 + c0 + cc] = u;
  }
}

// ---------------- 256x256 bf16 GEMM v8: fine 4-phase/K-tile, A+B LDS dbuf ----------------
// 8 waves (2M x 4N, 128x64/wave). Per K-tile: 4 phases (ks,mg): {8|4 ds_read,
// stage 1 half-tile of next K-tile, 16 MFMA(setprio), barrier}. vmcnt(0) once per
// K-tile (spill-immune). T2 both-sides swizzle, LDS 128 KiB (2 x 64KB K-tile buf).
// Epilogue + EPI variants from the verified r13 256² kernel.
template <int EPI>
__global__ __launch_bounds__(512, 2) void k_gemm(const short* __restrict__ A,
                                                 const short* __restrict__ B,
                                                 short* __restrict__ C,
                                                 short* __restrict__ o4,
                                                 const float* __restrict__ lsc,
                                                 int N, int K, int gx) {
  __shared__ short smem[65536];  // dbuf d at d*32768: A h0 +0, A h1 +8192, B h0 +16384, B h1 +24576
  const int nwg = gridDim.x;
  const int orig = blockIdx.x;
  const int wgid = (orig & 7) * (nwg >> 3) + (orig >> 3);
  const int bx = wgid % gx, by = wgid / gx;
  const int tid = threadIdx.x;
  const int lane = tid & 63, wid = tid >> 6;
  const int wm = wid >> 2, wn = wid & 3;  // 2M x 4N, 128x64 per wave
  const int m0 = by * 256, n0 = bx * 256;
  const int l15 = lane & 15, l4 = lane >> 4, l7 = lane & 7;
  const f32x4 fz = {0.f, 0.f, 0.f, 0.f};
  f32x4 acc[8][4];
#pragma unroll
  for (int m = 0; m < 8; ++m)
#pragma unroll
    for (int n = 0; n < 4; ++n) acc[m][n] = fz;
  const int srow = tid >> 3;  // 0..63
  const int cst = ((lane & 7) ^ ((lane >> 3) & 7)) * 8;  // pre-swizzled source slot
  const short* aP[2][2];
  const short* bP[2][2];
#pragma unroll
  for (int h = 0; h < 2; ++h)
#pragma unroll
    for (int q = 0; q < 2; ++q) {
      aP[h][q] = A + (size_t)(m0 + h * 128 + q * 64 + srow) * K + cst;
      bP[h][q] = B + (size_t)(n0 + h * 128 + q * 64 + srow) * K + cst;
    }
  const int nt = K >> 6;
  // prologue: stage K-tile 0 into dbuf 0 (A h0, A h1, B h0, B h1)
  {
    short* wb = smem;
    gload16(aP[0][0], wb + 0 + wid * 512);
    gload16(aP[0][1], wb + 4096 + wid * 512);
    gload16(aP[1][0], wb + 8192 + wid * 512);
    gload16(aP[1][1], wb + 12288 + wid * 512);
    gload16(bP[0][0], wb + 16384 + wid * 512);
    gload16(bP[0][1], wb + 20480 + wid * 512);
    gload16(bP[1][0], wb + 24576 + wid * 512);
    gload16(bP[1][1], wb + 28672 + wid * 512);
  }
  asm volatile("s_waitcnt vmcnt(0)" ::: "memory");
  __builtin_amdgcn_sched_barrier(0);
  __builtin_amdgcn_s_barrier();
  __builtin_amdgcn_sched_barrier(0);
  for (int kt = 0; kt < nt; ++kt) {
    const short* rb = smem + (kt & 1) * 32768;
    short* wb = smem + ((kt & 1) ^ 1) * 32768;
    const bool st = (kt + 1 < nt);
    const int ko = (kt + 1) * 64;
    s16x8 bfr[4];
#pragma unroll
    for (int p = 0; p < 4; ++p) {
      const int ks = p >> 1, mg = p & 1;
      const int slot = ((ks * 4 + l4) ^ l7) * 8;
      s16x8 af[4];
#pragma unroll
      for (int j = 0; j < 4; ++j)
        af[j] = *(const s16x8*)&rb[wm * 8192 + ((mg * 4 + j) * 16 + l15) * 64 + slot];
      if (mg == 0) {
#pragma unroll
        for (int n = 0; n < 4; ++n)
          bfr[n] = *(const s16x8*)&rb[16384 + (wn >> 1) * 8192 +
                                      ((wn & 1) * 64 + n * 16 + l15) * 64 + slot];
      }
      if (st) {  // stage half-tile p of next K-tile (A first: HBM-streamed)
        if (p == 0) { gload16(aP[0][0] + ko, wb + 0 + wid * 512);
                      gload16(aP[0][1] + ko, wb + 4096 + wid * 512); }
        if (p == 1) { gload16(aP[1][0] + ko, wb + 8192 + wid * 512);
                      gload16(aP[1][1] + ko, wb + 12288 + wid * 512); }
        if (p == 2) { gload16(bP[0][0] + ko, wb + 16384 + wid * 512);
                      gload16(bP[0][1] + ko, wb + 20480 + wid * 512); }
        if (p == 3) { gload16(bP[1][0] + ko, wb + 24576 + wid * 512);
                      gload16(bP[1][1] + ko, wb + 28672 + wid * 512); }
      }
      __builtin_amdgcn_s_setprio(1);
#pragma unroll
      for (int j = 0; j < 4; ++j)
#pragma unroll
        for (int n = 0; n < 4; ++n)
          acc[mg * 4 + j][n] = __builtin_amdgcn_mfma_f32_16x16x32_bf16(
              af[j], bfr[n], acc[mg * 4 + j][n], 0, 0, 0);
      __builtin_amdgcn_s_setprio(0);
      if (p == 3) asm volatile("s_waitcnt vmcnt(0)" ::: "memory");  // next tile landed
      __builtin_amdgcn_sched_barrier(0);
      __builtin_amdgcn_s_barrier();
      __builtin_amdgcn_sched_barrier(0);
    }
  }
  if (EPI == 2) {
#pragma unroll
    for (int b = 0; b < 2; ++b) {
      const int cb = n0 + wn * 64 + b * 32;
      if (cb < 1024) {
        float sc = 1.f;
        if (cb < 512) sc = __expf(fminf(lsc[cb >> 5], 4.605170185988092f));
#pragma unroll
        for (int m = 0; m < 8; ++m)
#pragma unroll
          for (int r = 0; r < 4; ++r) {
            float s0 = acc[m][2 * b][r], s1 = acc[m][2 * b + 1][r];
            float ss = s0 * s0 + s1 * s1;
            ss += __shfl_xor(ss, 1);
            ss += __shfl_xor(ss, 2);
            ss += __shfl_xor(ss, 4);
            ss += __shfl_xor(ss, 8);
            float mul = sc / fmaxf(sqrtf(ss), 1e-12f);
            acc[m][2 * b][r] = s0 * mul;
            acc[m][2 * b + 1][r] = s1 * mul;
          }
      }
    }
  }
  // ---- epilogue: 2 phases of 128 rows x 256 cols via ct[128][272] (r13-verified) ----
  short* ct = smem;
#pragma unroll
  for (int p = 0; p < 2; ++p) {
    if (p) __syncthreads();
    if (wm == p) {
#pragma unroll
      for (int m = 0; m < 8; ++m)
#pragma unroll
        for (int n = 0; n < 4; ++n)
#pragma unroll
          for (int r = 0; r < 4; ++r) {
            int lr = m * 16 + l4 * 4 + r;
            int lc = (wn * 64 + n * 16 + l15) ^ (((lr >> 2) & 3) << 4);
            ct[lr * 272 + lc] = f2b(acc[m][n][r]);
          }
    }
    __syncthreads();
#pragma unroll
    for (int uu = 0; uu < 8; ++uu) {
      int unit = uu * 512 + tid;  // 0..4095 = 128 rows x 32 slots
      int lr = unit >> 5, sl = unit & 31;
      int sx = (sl * 8) ^ (((lr >> 2) & 3) << 4);
      s16x8 v = *(const s16x8*)&ct[lr * 272 + sx];
      int grow = m0 + p * 128 + lr;
      int gcol = n0 + sl * 8;
      if (EPI != 1) {
        *(s16x8*)&C[(size_t)grow * N + gcol] = v;
      } else {
        int win = grow >> 6, nn = grow & 63;
        int b = win >> 6, whs = (win >> 3) & 7, wws = win & 7;
        int ih = nn >> 3, iw = nn & 7;
        int wh = (whs + 4) & 7, ww = (wws + 4) & 7;
        int cp = ww * 64 + wh * 8 + ih;
        int hp = iw * 8 + (gcol >> 6);
        int wp = gcol & 63;
        *(s16x8*)&o4[(((size_t)b * 512 + cp) * 64 + hp) * 64 + wp] = v;
      }
    }
  }
}

// ---------------- fused attention v3 (unchanged) ----------------
__global__ __launch_bounds__(256) void k_attn(const short* __restrict__ qkv,
                                              const float* __restrict__ btab_g,
                                              short* __restrict__ o_ws) {
  __shared__ float btab[3600];
  __shared__ short vts[2][2048];
  __shared__ short pts[4][1024];
  const int tid = threadIdx.x, lane = tid & 63, wid = tid >> 6;
  const int win = blockIdx.x;
  const int l15 = lane & 15, l4 = lane >> 4;
  const int qrow0 = wid * 16;
  for (int i = tid; i < 3600; i += 256) btab[i] = btab_g[i];
  int baddr[4][4];
#pragma unroll
  for (int n = 0; n < 4; ++n)
#pragma unroll
    for (int r = 0; r < 4; ++r) {
      int i_ = qrow0 + l4 * 4 + r, j_ = n * 16 + l15;
      int dih = (i_ >> 3) - (j_ >> 3) + 7;
      int diw = (i_ & 7) - (j_ & 7) + 7;
      baddr[n][r] = dih * 15 + diw;
    }
  __syncthreads();
  const short* base = qkv + (size_t)win * 64 * 1536;
  const f32x4 fz = {0.f, 0.f, 0.f, 0.f};
  f32x4 sump[4] = {fz, fz, fz, fz};
#pragma unroll 2
  for (int h = 0; h < 16; ++h) {
    s16x8 qf = *(const s16x8*)(base + (size_t)(qrow0 + l15) * 1536 + h * 32 + l4 * 8);
#pragma unroll
    for (int n = 0; n < 4; ++n) {
      s16x8 kf = *(const s16x8*)(base + (size_t)(n * 16 + l15) * 1536 + 512 + h * 32 + l4 * 8);
      f32x4 s = __builtin_amdgcn_mfma_f32_16x16x32_bf16(qf, kf, fz, 0, 0, 0);
#pragma unroll
      for (int r = 0; r < 4; ++r)
        sump[n][r] += __expf(s[r] + btab[h * 225 + baddr[n][r]]);
    }
  }
  f32x4 rden[4];
#pragma unroll
  for (int n = 0; n < 4; ++n)
#pragma unroll
    for (int r = 0; r < 4; ++r) rden[n][r] = 1.f / sump[n][r];
  char* pt = (char*)pts[wid];
  {
    int j = tid & 63, d0 = (tid >> 6) * 8;
    s16x8 vv = *(const s16x8*)(base + (size_t)j * 1536 + 1024 + d0);
#pragma unroll
    for (int jj = 0; jj < 8; ++jj) {
      int d = d0 + jj;
      *(short*)((char*)vts[0] + ((d * 128 + j * 2) ^ ((d & 7) << 4))) = vv[jj];
    }
  }
  __syncthreads();
  for (int h = 0; h < 16; ++h) {
    const char* vcur = (const char*)vts[h & 1];
    if (h < 15) {
      int j = tid & 63, d0 = (tid >> 6) * 8;
      s16x8 vv = *(const s16x8*)(base + (size_t)j * 1536 + 1024 + (h + 1) * 32 + d0);
      char* vnxt = (char*)vts[(h + 1) & 1];
#pragma unroll
      for (int jj = 0; jj < 8; ++jj) {
        int d = d0 + jj;
        *(short*)(vnxt + ((d * 128 + j * 2) ^ ((d & 7) << 4))) = vv[jj];
      }
    }
    s16x8 qf = *(const s16x8*)(base + (size_t)(qrow0 + l15) * 1536 + h * 32 + l4 * 8);
#pragma unroll
    for (int n = 0; n < 4; ++n) {
      s16x8 kf = *(const s16x8*)(base + (size_t)(n * 16 + l15) * 1536 + 512 + h * 32 + l4 * 8);
      f32x4 s = __builtin_amdgcn_mfma_f32_16x16x32_bf16(qf, kf, fz, 0, 0, 0);
#pragma unroll
      for (int r = 0; r < 4; ++r) {
        float pv = __expf(s[r] + btab[h * 225 + baddr[n][r]]) * rden[n][r];
        int i_loc = l4 * 4 + r, j_ = n * 16 + l15;
        *(short*)(pt + ((i_loc * 128 + j_ * 2) ^ ((i_loc & 7) << 4))) = f2b(pv);
      }
    }
    f32x4 oacc[2] = {fz, fz};
#pragma unroll
    for (int kb = 0; kb < 2; ++kb) {
      s16x8 af = *(const s16x8*)(pt + ((l15 * 128 + kb * 64 + l4 * 16) ^ ((l15 & 7) << 4)));
#pragma unroll
      for (int db = 0; db < 2; ++db) {
        int d = db * 16 + l15;
        s16x8 bf = *(const s16x8*)(vcur + ((d * 128 + kb * 64 + l4 * 16) ^ ((d & 7) << 4)));
        oacc[db] = __builtin_amdgcn_mfma_f32_16x16x32_bf16(af, bf, oacc[db], 0, 0, 0);
      }
    }
    short* ob = o_ws + ((size_t)win * 64 + qrow0) * 512 + h * 32;
#pragma unroll
    for (int db = 0; db < 2; ++db)
#pragma unroll
      for (int r = 0; r < 4; ++r)
        ob[(size_t)(l4 * 4 + r) * 512 + db * 16 + l15] = f2b(oacc[db][r]);
    __syncthreads();
  }
}

// ---------------- LN1 (unchanged) ----------------
__global__ __launch_bounds__(256) void k_ln1(const short* __restrict__ o4,
                                             const short* __restrict__ xt,
                                             const float* __restrict__ g1,
                                             const float* __restrict__ b1,
                                             const float* __restrict__ rs1,
                                             short* __restrict__ x2h) {
  __shared__ float reds[4][64], redq[4][64];
  __shared__ float mean_s[64], rstd_s[64];
  __shared__ short tile[128][66];
  const int tid = threadIdx.x;
  const int b = blockIdx.x >> 6, hp = blockIdx.x & 63;
  const int w = tid & 63, part = tid >> 6;
  const short* base = o4 + (size_t)b * 512 * 4096 + hp * 64;
  float s = 0.f, q = 0.f;
  for (int c = part; c < 512; c += 4) {
    float v = b2f(base[(size_t)c * 4096 + w]);
    s += v; q += v * v;
  }
  reds[part][w] = s; redq[part][w] = q;
  __syncthreads();
  if (tid < 64) {
    float S = 0.f, Q = 0.f;
    for (int i = 0; i < 4; ++i) { S += reds[i][tid]; Q += redq[i][tid]; }
    float m = S * (1.f / 512.f);
    float var = Q * (1.f / 512.f) - m * m;
    mean_s[tid] = m;
    rstd_s[tid] = rsqrtf(var + 8e-8f);
  }
  __syncthreads();
  const short* xtb = xt + (size_t)b * 512 * 4096 + hp * 64;
  for (int c0 = 0; c0 < 512; c0 += 128) {
    for (int cc = part; cc < 128; cc += 4) {
      int c = c0 + cc;
      float v = b2f(base[(size_t)c * 4096 + w]);
      float ln = (v - mean_s[w]) * rstd_s[w] * g1[c] + b1[c];
      float xv = rs1[c] * b2f(xtb[(size_t)c * 4096 + w]) + ln;
      tile[cc][w] = f2b(xv);
    }
    __syncthreads();
    short* xh = x2h + ((size_t)blockIdx.x * 64) * 512 + c0;
    for (int qd = tid; qd < 64 * 32; qd += 256) {
      int w_ = qd >> 5, cq = qd & 31, cc = cq * 4;
      ushort4 u;
      u.x = (unsigned short)tile[cc][w_];
      u.y = (unsigned short)tile[cc + 1][w_];
      u.z = (unsigned short)tile[cc + 2][w_];
      u.w = (unsigned short)tile[cc + 3][w_];
      *(ushort4*)&xh[(size_t)w_ * 512 + cc] = u;
    }
    __syncthreads();
  }
}

// ---------------- depthwise 3x3 + StarReLU (unchanged) ----------------
__global__ __launch_bounds__(256) void k_dwc2(const short* __restrict__ h1,
                                              const float* __restrict__ dw,
                                              const float* __restrict__ srs_p,
                                              const float* __restrict__ srb_p,
                                              short* __restrict__ h2) {
  __shared__ short tile[6 * 64 * 64];
  const int tid = threadIdx.x;
  const int cblk = blockIdx.x & 31;
  const int hq = (blockIdx.x >> 5) & 15;
  const int b = blockIdx.x >> 9;
  const int c0 = cblk * 64;
  const int h0 = hq * 4;
  for (int t = 0; t < 12; ++t) {
    int idx = t * 256 + tid;
    int cg = idx & 7;
    int wl = (idx >> 3) & 63;
    int rl = idx >> 9;
    int hr = h0 - 1 + rl;
    s16x8 v = {0, 0, 0, 0, 0, 0, 0, 0};
    if (hr >= 0 && hr < 64)
      v = *(const s16x8*)&h1[((size_t)b * 4096 + hr * 64 + wl) * 2048 + c0 + cg * 8];
    *(s16x8*)&tile[(rl * 64 + wl) * 64 + (cg ^ (wl & 7)) * 8] = v;
  }
  const int cg = tid & 7;
  const int wq = tid >> 3;
  float wt[9][8];
#pragma unroll
  for (int j = 0; j < 8; ++j) {
    int cch = c0 + cg * 8 + j;
#pragma unroll
    for (int t = 0; t < 9; ++t) wt[t][j] = dw[cch * 9 + t];
  }
  const float srs = *srs_p, srb = *srb_p;
  __syncthreads();
#pragma unroll
  for (int it = 0; it < 8; ++it) {
    int wl = wq + (it & 1) * 32;
    int rl = it >> 1;
    s16x8 ctr = *(const s16x8*)&tile[((rl + 1) * 64 + wl) * 64 + (cg ^ (wl & 7)) * 8];
    float acc[8];
#pragma unroll
    for (int j = 0; j < 8; ++j) acc[j] = b2f(ctr[j]);
#pragma unroll
    for (int dh = -1; dh <= 1; ++dh) {
      int row = rl + 1 + dh;
#pragma unroll
      for (int dwi = -1; dwi <= 1; ++dwi) {
        int wn = wl + dwi;
        if (wn < 0 || wn > 63) continue;
        s16x8 v = *(const s16x8*)&tile[(row * 64 + wn) * 64 + (cg ^ (wn & 7)) * 8];
        const float* wrow = wt[(dh + 1) * 3 + dwi + 1];
#pragma unroll
        for (int j = 0; j < 8; ++j) acc[j] += wrow[j] * b2f(v[j]);
      }
    }
    s16x8 o;
#pragma unroll
    for (int j = 0; j < 8; ++j) {
      float rr = fmaxf(acc[j], 0.f);
      o[j] = f2b(srs * rr * rr + srb);
    }
    *(s16x8*)&h2[((size_t)b * 4096 + (h0 + rl) * 64 + wl) * 2048 + c0 + cg * 8] = o;
  }
}

// ---------------- final (unchanged) ----------------
__global__ __launch_bounds__(256) void k_final(const short* __restrict__ y,
                                               const short* __restrict__ x2h,
                                               const float* __restrict__ g2,
                                               const float* __restrict__ b2p,
                                               const float* __restrict__ rs2,
                                               float* __restrict__ out) {
  __shared__ short yt[64][132];
  __shared__ short xt2[64][132];
  __shared__ float reds[4][64], redq[4][64];
  __shared__ float mean_s[64], rstd_s[64];
  const int tid = threadIdx.x;
  const int b = blockIdx.x >> 6, hh = blockIdx.x & 63;
  const int w = tid & 63, part = tid >> 6;
  const short* yb = y + (size_t)blockIdx.x * 64 * 512;
  const short* xb = x2h + (size_t)blockIdx.x * 64 * 512;
  float s = 0.f, q = 0.f;
  for (int c0 = 0; c0 < 512; c0 += 128) {
    for (int qd = tid; qd < 64 * 32; qd += 256) {
      int w_ = qd >> 5, g = qd & 31;
      *(ushort4*)&yt[w_][g * 4] = *(const ushort4*)&yb[(size_t)w_ * 512 + c0 + g * 4];
    }
    __syncthreads();
    for (int cc = part * 32; cc < part * 32 + 32; ++cc) {
      float v = b2f(yt[w][cc]);
      s += v; q += v * v;
    }
    __syncthreads();
  }
  reds[part][w] = s; redq[part][w] = q;
  __syncthreads();
  if (tid < 64) {
    float S = 0.f, Q = 0.f;
    for (int i = 0; i < 4; ++i) { S += reds[i][tid]; Q += redq[i][tid]; }
    float m = S * (1.f / 512.f);
    float var = Q * (1.f / 512.f) - m * m;
    mean_s[tid] = m;
    rstd_s[tid] = rsqrtf(var + 8e-8f);
  }
  __syncthreads();
  float* ob = out + (size_t)b * 512 * 4096 + hh * 64;
  for (int c0 = 0; c0 < 512; c0 += 128) {
    for (int qd = tid; qd < 64 * 32; qd += 256) {
      int w_ = qd >> 5, g = qd & 31;
      *(ushort4*)&yt[w_][g * 4] = *(const ushort4*)&yb[(size_t)w_ * 512 + c0 + g * 4];
      *(ushort4*)&xt2[w_][g * 4] = *(const ushort4*)&xb[(size_t)w_ * 512 + c0 + g * 4];
    }
    __syncthreads();
    for (int it = 0; it < 32; ++it) {
      int c = c0 + it * 4 + part;
      float yv = b2f(yt[w][c - c0]);
      float lnv = (yv - mean_s[w]) * rstd_s[w] * g2[c] + b2p[c];
      float xv = b2f(xt2[w][c - c0]);
      ob[(size_t)c * 4096 + w] = rs2[c] * xv + lnv;
    }
    __syncthreads();
  }
}

extern "C" void kernel_launch(void* const* d_in, const int* in_sizes, int n_in,
                              void* d_out, int out_size, void* d_ws, size_t ws_size,
                              hipStream_t stream) {
  (void)in_sizes; (void)n_in; (void)out_size; (void)ws_size;
  const float* x      = (const float*)d_in[0];
  const float* lpu_w  = (const float*)d_in[1];
  const float* qkv_w  = (const float*)d_in[2];
  const float* out_w  = (const float*)d_in[3];
  const float* cpb_w1 = (const float*)d_in[4];
  const float* cpb_w2 = (const float*)d_in[5];
  const float* lsc    = (const float*)d_in[6];
  const float* g1     = (const float*)d_in[7];
  const float* b1     = (const float*)d_in[8];
  const float* g2     = (const float*)d_in[9];
  const float* b2v    = (const float*)d_in[10];
  const float* pw1_w  = (const float*)d_in[11];
  const float* dw_w   = (const float*)d_in[12];
  const float* pw2_w  = (const float*)d_in[13];
  const float* srs    = (const float*)d_in[14];
  const float* srb    = (const float*)d_in[15];
  const float* rs1    = (const float*)d_in[16];
  const float* rs2    = (const float*)d_in[17];

  char* ws = (char*)d_ws;
  float* btab   = (float*)(ws + 0);
  short* wbq    = (short*)(ws + 16384);
  short* wbo    = (short*)(ws + 1589248);
  short* wb1    = (short*)(ws + 2113536);
  short* wb2    = (short*)(ws + 4210688);
  short* x_temp = (short*)(ws + 8388608);
  short* xw     = (short*)(ws + 75497472);
  short* qkv    = (short*)(ws + 142606336);
  short* o_ws   = (short*)(ws + 343932928);
  short* o4     = (short*)(ws + 75497472);    // = xw (dead)
  short* x2h    = (short*)(ws + 142606336);   // = qkv head (dead); live until k_final
  short* h1     = (short*)(ws + 209715200);   // = qkv tail (dead), 128 MiB
  short* h2     = (short*)(ws + 8388608);     // = x_temp+xw (dead), 128 MiB
  short* yb     = (short*)(ws + 343932928);   // = o_ws (dead)

  k_f2b4<<<3072, 256, 0, stream>>>(qkv_w, wbq, out_w, wbo, pw1_w, wb1, pw2_w, wb2);
  k_cpb<<<225, 64, 0, stream>>>(cpb_w1, cpb_w2, btab);
  k_lpu<<<8192, 256, 0, stream>>>(x, lpu_w, x_temp);
  k_xpose<<<4096, 256, 0, stream>>>(x_temp, xw);
  k_gemm<2><<<1536, 512, 0, stream>>>(xw, wbq, qkv, nullptr, lsc, 1536, 512, 6);
  k_attn<<<1024, 256, 0, stream>>>(qkv, btab, o_ws);
  k_gemm<1><<<512, 512, 0, stream>>>(o_ws, wbo, nullptr, o4, nullptr, 512, 512, 2);
  k_ln1<<<1024, 256, 0, stream>>>(o4, x_temp, g1, b1, rs1, x2h);
  for (int ch = 0; ch < 2; ++ch) {
    const size_t tok0 = (size_t)ch * 8 * 4096;
    k_gemm<0><<<1024, 512, 0, stream>>>(x2h + tok0 * 512, wb1, h1, nullptr, nullptr, 2048, 512, 8);
    k_dwc2<<<4096, 256, 0, stream>>>(h1, dw_w, srs, srb, h2);
    k_gemm<0><<<256, 512, 0, stream>>>(h2, wb2, yb + tok0 * 512, nullptr, nullptr, 512, 2048, 2);
  }
  k_final<<<1024, 256, 0, stream>>>(yb, x2h, g2, b2v, rs2, (float*)d_out);
}

// Round 17
// 1092.243 us; speedup vs baseline: 1.0714x; 1.0714x over previous
//
#include <hip/hip_runtime.h>
#include <hip/hip_bf16.h>
#include <stdint.h>

// B=16, C=512, H=W=64, nh=16, hd=32, ws=8, shift=4, N=64 tok/window, Bw=1024,
// hid=2048. Softmax is over the HEAD axis (faithful bug) -> attention mask is
// head-uniform and cancels; logits <= 26 so exp() without max-sub is safe.
// QK row-normalization (+ logits scale on q) is folded into the qkv GEMM
// epilogue (EPI=2). Residual x2 lives only as bf16 NHWC (x2h); no fp32 copy.
//
// Workspace map (bytes), REQUIRES ws_size >= 411,041,792 (392 MiB):
//   [0        ,14400    ) btab f32 [16][225]
//   [16384    ,1589248  ) wbq bf16 [1536][512]
//   [1589248  ,2113536  ) wbo bf16 [512][512]
//   [2113536  ,4210688  ) wb1 bf16 [2048][512]
//   [4210688  ,6307840  ) wb2 bf16 [512][2048]
//   [8388608  ,75497472 ) x_temp bf16 NCHW          (dead after ln1; reused by h2)
//   [75497472 ,142606336) xw bf16 [65536][512]      (dead after qkv gemm; reused by o4, then h2)
//   [142606336,343932928) qkv bf16 [65536][1536]    (dead after attn; head reused by x2h, tail by h1)
//   [343932928,411041792) o_ws bf16 [65536][512]    (dead after out gemm; reused by y)
// x2h stays live until k_final (region [142606336,209715200) untouched after ln1).

typedef float f32x4 __attribute__((ext_vector_type(4)));
typedef short s16x8 __attribute__((ext_vector_type(8)));

__device__ __forceinline__ float b2f(short u) {
  return __uint_as_float(((unsigned)(unsigned short)u) << 16);
}
__device__ __forceinline__ short f2b(float f) {
  __hip_bfloat16 h = __float2bfloat16(f);  // RNE; lowers to v_cvt_pk_bf16_f32
  short s;
  __builtin_memcpy(&s, &h, 2);
  return s;
}
__device__ __forceinline__ void gload16(const void* g, void* l) {
  __builtin_amdgcn_global_load_lds((const unsigned int*)g, (unsigned int*)l, 16, 0, 0);
}

// ---------------- fp32 -> bf16 weight conversion (all 4 weights, one launch) ----------------
__global__ __launch_bounds__(256) void k_f2b4(const float* __restrict__ s0, short* __restrict__ d0,
                                              const float* __restrict__ s1, short* __restrict__ d1,
                                              const float* __restrict__ s2, short* __restrict__ d2,
                                              const float* __restrict__ s3, short* __restrict__ d3) {
  int b = blockIdx.x;
  const float* s;
  short* d;
  int base;
  if (b < 768) { s = s0; d = d0; base = b * 1024; }
  else if (b < 1024) { s = s1; d = d1; base = (b - 768) * 1024; }
  else if (b < 2048) { s = s2; d = d2; base = (b - 1024) * 1024; }
  else { s = s3; d = d3; base = (b - 2048) * 1024; }
  int i = base + threadIdx.x * 4;
  f32x4 v = *(const f32x4*)&s[i];
  ushort4 o;
  o.x = (unsigned short)f2b(v[0]);
  o.y = (unsigned short)f2b(v[1]);
  o.z = (unsigned short)f2b(v[2]);
  o.w = (unsigned short)f2b(v[3]);
  *(ushort4*)&d[i] = o;
}

// ---------------- CPB bias table: btab[h][rpi] = 16*sigmoid(mlp(table[rpi])) ----------------
__global__ __launch_bounds__(64) void k_cpb(const float* __restrict__ w1,
                                            const float* __restrict__ w2,
                                            float* __restrict__ btab) {
  const int r = blockIdx.x;      // 0..224
  const int lane = threadIdx.x;  // 0..63
  const int ri = r / 15, rj = r % 15;
  float th = (float)(ri - 7) * (8.f / 7.f);
  float tw = (float)(rj - 7) * (8.f / 7.f);
  float gh = copysignf(log2f(fabsf(th) + 1.f) * (1.f / 3.f), th);
  float gw = copysignf(log2f(fabsf(tw) + 1.f) * (1.f / 3.f), tw);
  const int h = lane >> 2, pp = lane & 3;
  float acc = 0.f;
  for (int k = 0; k < 128; ++k) {
    int hh = pp * 128 + k;
    float a = gh * w1[hh * 2] + gw * w1[hh * 2 + 1];
    float r6 = fminf(fmaxf(a + 3.f, 0.f), 6.f);
    float hsw = a * r6 * (1.f / 6.f);
    acc += hsw * w2[h * 512 + hh];
  }
  acc += __shfl_xor(acc, 1);
  acc += __shfl_xor(acc, 2);
  if ((lane & 3) == 0) btab[h * 225 + r] = 16.f / (1.f + __expf(-acc));
}

// ---------------- LPU: x + depthwise 3x3 (SAME), out bf16 NCHW ----------------
__global__ __launch_bounds__(256) void k_lpu(const float* __restrict__ x,
                                             const float* __restrict__ lw,
                                             short* __restrict__ xt) {
  __shared__ float img[64 * 68];
  const int bc = blockIdx.x;  // b*512+c
  const int c = bc & 511;
  const float* img_g = x + (size_t)bc * 4096;
  short* outp = xt + (size_t)bc * 4096;
  const int tid = threadIdx.x;
#pragma unroll
  for (int t = 0; t < 4; ++t) {
    int idx = t * 256 + tid;
    int h = idx >> 4, w4 = (idx & 15) * 4;
    f32x4 v = *(const f32x4*)&img_g[h * 64 + w4];
    *(f32x4*)&img[h * 68 + w4] = v;
  }
  float wreg[9];
#pragma unroll
  for (int t = 0; t < 9; ++t) wreg[t] = lw[c * 9 + t];
  __syncthreads();
  const int hb = tid >> 4, w0 = (tid & 15) * 4;
#pragma unroll
  for (int g = 0; g < 4; ++g) {
    int h = hb + g * 16;
    float row[3][6];
#pragma unroll
    for (int dr = 0; dr < 3; ++dr) {
      int hh = h - 1 + dr;
      if (hh < 0 || hh > 63) {
#pragma unroll
        for (int j = 0; j < 6; ++j) row[dr][j] = 0.f;
      } else {
        f32x4 m = *(const f32x4*)&img[hh * 68 + w0];
        row[dr][1] = m[0]; row[dr][2] = m[1]; row[dr][3] = m[2]; row[dr][4] = m[3];
        row[dr][0] = (w0 > 0) ? img[hh * 68 + w0 - 1] : 0.f;
        row[dr][5] = (w0 < 60) ? img[hh * 68 + w0 + 4] : 0.f;
      }
    }
    ushort4 o;
    unsigned short op[4];
#pragma unroll
    for (int p = 0; p < 4; ++p) {
      float acc = row[1][p + 1];
#pragma unroll
      for (int dr = 0; dr < 3; ++dr)
#pragma unroll
        for (int dc = 0; dc < 3; ++dc)
          acc += wreg[dr * 3 + dc] * row[dr][p + dc];
      op[p] = (unsigned short)f2b(acc);
    }
    o.x = op[0]; o.y = op[1]; o.z = op[2]; o.w = op[3];
    *(ushort4*)&outp[h * 64 + w0] = o;
  }
}

// ---------------- roll(-4,-4) over (tokens,channels) + window partition ----------------
// v2: vectorized staging (s16x8 global loads, 16 B/lane).
__global__ __launch_bounds__(256) void k_xpose(const short* __restrict__ xt,
                                               short* __restrict__ xw) {
  __shared__ short tile[64][132];
  const int tid = threadIdx.x;
  const int cq = blockIdx.x & 3;
  const int h = (blockIdx.x >> 2) & 63;
  const int b = blockIdx.x >> 8;
  const int c0 = cq * 128;
#pragma unroll
  for (int t = 0; t < 4; ++t) {
    int u = t * 256 + tid;            // 0..1023 = 128 cc x 8 ww-octets
    int ww0 = (u & 7) * 8, cc = u >> 3;
    int csrc = (c0 + cc + 4) & 511;
    s16x8 v = *(const s16x8*)&xt[(((size_t)b * 512 + csrc) * 64 + h) * 64 + ww0];
#pragma unroll
    for (int j = 0; j < 8; ++j) tile[ww0 + j][cc] = v[j];
  }
  __syncthreads();
  for (int qd = tid; qd < 64 * 32; qd += 256) {
    int ws_ = qd >> 5, cqq = qd & 31, cc = cqq * 4;
    int t = (h * 64 + ws_ + 4092) & 4095;
    int hd = t >> 6, wd = t & 63;
    int tok = (b * 64 + (hd >> 3) * 8 + (wd >> 3)) * 64 + (hd & 7) * 8 + (wd & 7);
    ushort4 u = *(const ushort4*)&tile[ws_][cc];
    *(ushort4*)&xw[(size_t)tok * 512 + c0 + cc] = u;
  }
}

// ---------------- 128x128 bf16 GEMM v5: dbuf stage-early + counted vmcnt (T4) ----------------
// 8 waves (2M x 4N, 64x32/wave); raw s_barrier with vmcnt(4) -> prefetch loads stay
// in flight across the barrier. T2 both-sides swizzle; T5 setprio. Epilogue: 2-phase
// LDS transpose -> ushort8. EPI 0: bf16 C. EPI 1: scatter o4. EPI 2: q/k norm.
template <int EPI>
__global__ __launch_bounds__(512) void k_gemm(const short* __restrict__ A,
                                              const short* __restrict__ B,
                                              short* __restrict__ C,
                                              short* __restrict__ o4,
                                              const float* __restrict__ lsc,
                                              int N, int K, int gx) {
  __shared__ short smem[2 * 16384];  // buf b: A at b*16384, B at +8192 (64 KiB)
  const int nwg = gridDim.x;
  const int orig = blockIdx.x;
  const int wgid = (orig & 7) * (nwg >> 3) + (orig >> 3);
  const int bx = wgid % gx, by = wgid / gx;
  const int tid = threadIdx.x;
  const int lane = tid & 63, wid = tid >> 6;  // 8 waves
  const int wm = wid >> 2, wn = wid & 3;      // 2M x 4N
  const int m0 = by * 128, n0 = bx * 128;
  const f32x4 fz = {0.f, 0.f, 0.f, 0.f};
  f32x4 acc[4][2];
#pragma unroll
  for (int m = 0; m < 4; ++m) { acc[m][0] = fz; acc[m][1] = fz; }
  const int rst = lane >> 3;
  const int cst = ((lane & 7) ^ rst) * 8;  // pre-swizzled source column slot
  const int l15 = lane & 15, l4 = lane >> 4, l7 = lane & 7;
  const short* ag[2];
  const short* bg[2];
#pragma unroll
  for (int l = 0; l < 2; ++l) {
    int h8 = wid * 2 + l;  // 0..15 -> rows h8*8+rst
    ag[l] = A + (size_t)(m0 + h8 * 8 + rst) * K + cst;
    bg[l] = B + (size_t)(n0 + h8 * 8 + rst) * K + cst;
  }
  const int nt = K >> 6;
  auto STAGE = [&](int b) {  // 4 gload_lds per thread
    short* as = smem + b * 16384;
    short* bs = as + 8192;
#pragma unroll
    for (int l = 0; l < 2; ++l) {
      int h8 = wid * 2 + l;
      gload16(ag[l], as + h8 * 512);
      gload16(bg[l], bs + h8 * 512);
      ag[l] += 64;
      bg[l] += 64;
    }
  };
  STAGE(0);
  for (int kt = 0; kt < nt; ++kt) {
    const int cur = kt & 1;
    if (kt + 1 < nt) {
      STAGE(cur ^ 1);  // 4 more loads in flight
      asm volatile("s_waitcnt vmcnt(4)" ::: "memory");  // oldest 4 (buf[cur]) done
    } else {
      asm volatile("s_waitcnt vmcnt(0)" ::: "memory");
    }
    __builtin_amdgcn_s_barrier();            // all waves: buf[cur] ready
    __builtin_amdgcn_sched_barrier(0);       // pin ds_reads below the barrier
    const short* as = smem + cur * 16384;
    const short* bs = as + 8192;
    __builtin_amdgcn_s_setprio(1);
#pragma unroll
    for (int ks = 0; ks < 2; ++ks) {
      s16x8 af[4], bfr[2];
#pragma unroll
      for (int m = 0; m < 4; ++m)
        af[m] = *(const s16x8*)&as[(wm * 64 + m * 16 + l15) * 64 + (((ks * 4 + l4) ^ l7) * 8)];
#pragma unroll
      for (int n = 0; n < 2; ++n)
        bfr[n] = *(const s16x8*)&bs[(wn * 32 + n * 16 + l15) * 64 + (((ks * 4 + l4) ^ l7) * 8)];
#pragma unroll
      for (int m = 0; m < 4; ++m)
#pragma unroll
        for (int n = 0; n < 2; ++n)
          acc[m][n] = __builtin_amdgcn_mfma_f32_16x16x32_bf16(af[m], bfr[n],
                                                              acc[m][n], 0, 0, 0);
    }
    __builtin_amdgcn_s_setprio(0);
    __builtin_amdgcn_sched_barrier(0);       // keep reads above the barrier
    __builtin_amdgcn_s_barrier();            // all waves done reading buf[cur]
    __builtin_amdgcn_sched_barrier(0);       // pin next STAGE below the barrier
  }
  if (EPI == 2) {
    const int cb = n0 + wn * 32;  // this wave's 32-col head band
    if (cb < 1024) {
      float sc = 1.f;
      if (cb < 512) sc = __expf(fminf(lsc[cb >> 5], 4.605170185988092f));
#pragma unroll
      for (int m = 0; m < 4; ++m)
#pragma unroll
        for (int r = 0; r < 4; ++r) {
          float s0 = acc[m][0][r], s1 = acc[m][1][r];
          float ss = s0 * s0 + s1 * s1;
          ss += __shfl_xor(ss, 1);
          ss += __shfl_xor(ss, 2);
          ss += __shfl_xor(ss, 4);
          ss += __shfl_xor(ss, 8);
          float mul = sc / fmaxf(sqrtf(ss), 1e-12f);
          acc[m][0][r] = s0 * mul;
          acc[m][1][r] = s1 * mul;
        }
    }
  }
  // ---- epilogue: 2 phases of 64 rows, ct[64][136], coalesced ushort8 ----
  short* ct = smem;
#pragma unroll
  for (int p = 0; p < 2; ++p) {
    if (p) __syncthreads();
    if (wm == p) {
#pragma unroll
      for (int m = 0; m < 4; ++m)
#pragma unroll
        for (int n = 0; n < 2; ++n)
#pragma unroll
          for (int r = 0; r < 4; ++r) {
            int lr = m * 16 + l4 * 4 + r;
            int lc = wn * 32 + n * 16 + l15;
            ct[lr * 136 + lc] = f2b(acc[m][n][r]);
          }
    }
    __syncthreads();
#pragma unroll
    for (int u = 0; u < 2; ++u) {
      int unit = u * 512 + tid;          // 0..1023 = 64 rows x 16 slots
      int lr = unit >> 4, cs = unit & 15;
      s16x8 v = *(const s16x8*)&ct[lr * 136 + cs * 8];
      int grow = m0 + p * 64 + lr;
      int gcol = n0 + cs * 8;
      if (EPI != 1) {
        *(s16x8*)&C[(size_t)grow * N + gcol] = v;
      } else {
        int win = grow >> 6, nn = grow & 63;
        int b = win >> 6, whs = (win >> 3) & 7, wws = win & 7;
        int ih = nn >> 3, iw = nn & 7;
        int wh = (whs + 4) & 7, ww = (wws + 4) & 7;
        int cp = ww * 64 + wh * 8 + ih;
        int hp = iw * 8 + (gcol >> 6);
        int wp = gcol & 63;
        *(s16x8*)&o4[(((size_t)b * 512 + cp) * 64 + hp) * 64 + wp] = v;
      }
    }
  }
}

// ---------------- fused attention v3: pre-normalized q,k; wave owns 16 rows x all heads ----------------
__global__ __launch_bounds__(256) void k_attn(const short* __restrict__ qkv,
                                              const float* __restrict__ btab_g,
                                              short* __restrict__ o_ws) {
  __shared__ float btab[3600];      // [h][225]
  __shared__ short vts[2][2048];    // V^T[32][64] swizzled, double-buffered
  __shared__ short pts[4][1024];    // per-wave P[16][64] swizzled
  const int tid = threadIdx.x, lane = tid & 63, wid = tid >> 6;
  const int win = blockIdx.x;
  const int l15 = lane & 15, l4 = lane >> 4;
  const int qrow0 = wid * 16;
  for (int i = tid; i < 3600; i += 256) btab[i] = btab_g[i];
  int baddr[4][4];
#pragma unroll
  for (int n = 0; n < 4; ++n)
#pragma unroll
    for (int r = 0; r < 4; ++r) {
      int i_ = qrow0 + l4 * 4 + r, j_ = n * 16 + l15;
      int dih = (i_ >> 3) - (j_ >> 3) + 7;
      int diw = (i_ & 7) - (j_ & 7) + 7;
      baddr[n][r] = dih * 15 + diw;
    }
  __syncthreads();
  const short* base = qkv + (size_t)win * 64 * 1536;
  const f32x4 fz = {0.f, 0.f, 0.f, 0.f};
  f32x4 sump[4] = {fz, fz, fz, fz};
#pragma unroll 2
  for (int h = 0; h < 16; ++h) {
    s16x8 qf = *(const s16x8*)(base + (size_t)(qrow0 + l15) * 1536 + h * 32 + l4 * 8);
#pragma unroll
    for (int n = 0; n < 4; ++n) {
      s16x8 kf = *(const s16x8*)(base + (size_t)(n * 16 + l15) * 1536 + 512 + h * 32 + l4 * 8);
      f32x4 s = __builtin_amdgcn_mfma_f32_16x16x32_bf16(qf, kf, fz, 0, 0, 0);
#pragma unroll
      for (int r = 0; r < 4; ++r)
        sump[n][r] += __expf(s[r] + btab[h * 225 + baddr[n][r]]);
    }
  }
  f32x4 rden[4];
#pragma unroll
  for (int n = 0; n < 4; ++n)
#pragma unroll
    for (int r = 0; r < 4; ++r) rden[n][r] = 1.f / sump[n][r];
  char* pt = (char*)pts[wid];
  {
    int j = tid & 63, d0 = (tid >> 6) * 8;
    s16x8 vv = *(const s16x8*)(base + (size_t)j * 1536 + 1024 + d0);
#pragma unroll
    for (int jj = 0; jj < 8; ++jj) {
      int d = d0 + jj;
      *(short*)((char*)vts[0] + ((d * 128 + j * 2) ^ ((d & 7) << 4))) = vv[jj];
    }
  }
  __syncthreads();
  for (int h = 0; h < 16; ++h) {
    const char* vcur = (const char*)vts[h & 1];
    if (h < 15) {
      int j = tid & 63, d0 = (tid >> 6) * 8;
      s16x8 vv = *(const s16x8*)(base + (size_t)j * 1536 + 1024 + (h + 1) * 32 + d0);
      char* vnxt = (char*)vts[(h + 1) & 1];
#pragma unroll
      for (int jj = 0; jj < 8; ++jj) {
        int d = d0 + jj;
        *(short*)(vnxt + ((d * 128 + j * 2) ^ ((d & 7) << 4))) = vv[jj];
      }
    }
    s16x8 qf = *(const s16x8*)(base + (size_t)(qrow0 + l15) * 1536 + h * 32 + l4 * 8);
#pragma unroll
    for (int n = 0; n < 4; ++n) {
      s16x8 kf = *(const s16x8*)(base + (size_t)(n * 16 + l15) * 1536 + 512 + h * 32 + l4 * 8);
      f32x4 s = __builtin_amdgcn_mfma_f32_16x16x32_bf16(qf, kf, fz, 0, 0, 0);
#pragma unroll
      for (int r = 0; r < 4; ++r) {
        float pv = __expf(s[r] + btab[h * 225 + baddr[n][r]]) * rden[n][r];
        int i_loc = l4 * 4 + r, j_ = n * 16 + l15;
        *(short*)(pt + ((i_loc * 128 + j_ * 2) ^ ((i_loc & 7) << 4))) = f2b(pv);
      }
    }
    f32x4 oacc[2] = {fz, fz};
#pragma unroll
    for (int kb = 0; kb < 2; ++kb) {
      s16x8 af = *(const s16x8*)(pt + ((l15 * 128 + kb * 64 + l4 * 16) ^ ((l15 & 7) << 4)));
#pragma unroll
      for (int db = 0; db < 2; ++db) {
        int d = db * 16 + l15;
        s16x8 bf = *(const s16x8*)(vcur + ((d * 128 + kb * 64 + l4 * 16) ^ ((d & 7) << 4)));
        oacc[db] = __builtin_amdgcn_mfma_f32_16x16x32_bf16(af, bf, oacc[db], 0, 0, 0);
      }
    }
    short* ob = o_ws + ((size_t)win * 64 + qrow0) * 512 + h * 32;
#pragma unroll
    for (int db = 0; db < 2; ++db)
#pragma unroll
      for (int r = 0; r < 4; ++r)
        ob[(size_t)(l4 * 4 + r) * 512 + db * 16 + l15] = f2b(oacc[db][r]);
    __syncthreads();
  }
}

// ---------------- LN1 over channels of o4 + residual rs1*x_temp -> x2h (bf16 NHWC only) ----------------
__global__ __launch_bounds__(256) void k_ln1(const short* __restrict__ o4,
                                             const short* __restrict__ xt,
                                             const float* __restrict__ g1,
                                             const float* __restrict__ b1,
                                             const float* __restrict__ rs1,
                                             short* __restrict__ x2h) {
  __shared__ float reds[4][64], redq[4][64];
  __shared__ float mean_s[64], rstd_s[64];
  __shared__ short tile[128][66];
  const int tid = threadIdx.x;
  const int b = blockIdx.x >> 6, hp = blockIdx.x & 63;
  const int w = tid & 63, part = tid >> 6;
  const short* base = o4 + (size_t)b * 512 * 4096 + hp * 64;
  float s = 0.f, q = 0.f;
  for (int c = part; c < 512; c += 4) {
    float v = b2f(base[(size_t)c * 4096 + w]);
    s += v; q += v * v;
  }
  reds[part][w] = s; redq[part][w] = q;
  __syncthreads();
  if (tid < 64) {
    float S = 0.f, Q = 0.f;
    for (int i = 0; i < 4; ++i) { S += reds[i][tid]; Q += redq[i][tid]; }
    float m = S * (1.f / 512.f);
    float var = Q * (1.f / 512.f) - m * m;
    mean_s[tid] = m;
    rstd_s[tid] = rsqrtf(var + 8e-8f);
  }
  __syncthreads();
  const short* xtb = xt + (size_t)b * 512 * 4096 + hp * 64;
  for (int c0 = 0; c0 < 512; c0 += 128) {
    for (int cc = part; cc < 128; cc += 4) {
      int c = c0 + cc;
      float v = b2f(base[(size_t)c * 4096 + w]);
      float ln = (v - mean_s[w]) * rstd_s[w] * g1[c] + b1[c];
      float xv = rs1[c] * b2f(xtb[(size_t)c * 4096 + w]) + ln;
      tile[cc][w] = f2b(xv);
    }
    __syncthreads();
    short* xh = x2h + ((size_t)blockIdx.x * 64) * 512 + c0;
    for (int qd = tid; qd < 64 * 32; qd += 256) {
      int w_ = qd >> 5, cq = qd & 31, cc = cq * 4;
      ushort4 u;
      u.x = (unsigned short)tile[cc][w_];
      u.y = (unsigned short)tile[cc + 1][w_];
      u.z = (unsigned short)tile[cc + 2][w_];
      u.w = (unsigned short)tile[cc + 3][w_];
      *(ushort4*)&xh[(size_t)w_ * 512 + cc] = u;
    }
    __syncthreads();
  }
}

// ---------------- depthwise 3x3 on h1 (2048ch NHWC bf16, 8-image chunk) + StarReLU ----------------
__global__ __launch_bounds__(256) void k_dwc2(const short* __restrict__ h1,
                                              const float* __restrict__ dw,
                                              const float* __restrict__ srs_p,
                                              const float* __restrict__ srb_p,
                                              short* __restrict__ h2) {
  __shared__ short tile[6 * 64 * 64];  // [row][w][cg^(w&7)][8]
  const int tid = threadIdx.x;
  const int cblk = blockIdx.x & 31;
  const int hq = (blockIdx.x >> 5) & 15;
  const int b = blockIdx.x >> 9;
  const int c0 = cblk * 64;
  const int h0 = hq * 4;
  for (int t = 0; t < 12; ++t) {
    int idx = t * 256 + tid;
    int cg = idx & 7;
    int wl = (idx >> 3) & 63;
    int rl = idx >> 9;
    int hr = h0 - 1 + rl;
    s16x8 v = {0, 0, 0, 0, 0, 0, 0, 0};
    if (hr >= 0 && hr < 64)
      v = *(const s16x8*)&h1[((size_t)b * 4096 + hr * 64 + wl) * 2048 + c0 + cg * 8];
    *(s16x8*)&tile[(rl * 64 + wl) * 64 + (cg ^ (wl & 7)) * 8] = v;
  }
  const int cg = tid & 7;
  const int wq = tid >> 3;
  float wt[9][8];
#pragma unroll
  for (int j = 0; j < 8; ++j) {
    int cch = c0 + cg * 8 + j;
#pragma unroll
    for (int t = 0; t < 9; ++t) wt[t][j] = dw[cch * 9 + t];
  }
  const float srs = *srs_p, srb = *srb_p;
  __syncthreads();
#pragma unroll
  for (int it = 0; it < 8; ++it) {
    int wl = wq + (it & 1) * 32;
    int rl = it >> 1;
    s16x8 ctr = *(const s16x8*)&tile[((rl + 1) * 64 + wl) * 64 + (cg ^ (wl & 7)) * 8];
    float acc[8];
#pragma unroll
    for (int j = 0; j < 8; ++j) acc[j] = b2f(ctr[j]);
#pragma unroll
    for (int dh = -1; dh <= 1; ++dh) {
      int row = rl + 1 + dh;
#pragma unroll
      for (int dwi = -1; dwi <= 1; ++dwi) {
        int wn = wl + dwi;
        if (wn < 0 || wn > 63) continue;
        s16x8 v = *(const s16x8*)&tile[(row * 64 + wn) * 64 + (cg ^ (wn & 7)) * 8];
        const float* wrow = wt[(dh + 1) * 3 + dwi + 1];
#pragma unroll
        for (int j = 0; j < 8; ++j) acc[j] += wrow[j] * b2f(v[j]);
      }
    }
    s16x8 o;
#pragma unroll
    for (int j = 0; j < 8; ++j) {
      float rr = fmaxf(acc[j], 0.f);
      o[j] = f2b(srs * rr * rr + srb);
    }
    *(s16x8*)&h2[((size_t)b * 4096 + (h0 + rl) * 64 + wl) * 2048 + c0 + cg * 8] = o;
  }
}

// ---------------- final: out = rs2*x2h + LN_c(y), NCHW f32 output ----------------
__global__ __launch_bounds__(256) void k_final(const short* __restrict__ y,
                                               const short* __restrict__ x2h,
                                               const float* __restrict__ g2,
                                               const float* __restrict__ b2p,
                                               const float* __restrict__ rs2,
                                               float* __restrict__ out) {
  __shared__ short yt[64][132];
  __shared__ short xt2[64][132];
  __shared__ float reds[4][64], redq[4][64];
  __shared__ float mean_s[64], rstd_s[64];
  const int tid = threadIdx.x;
  const int b = blockIdx.x >> 6, hh = blockIdx.x & 63;
  const int w = tid & 63, part = tid >> 6;
  const short* yb = y + (size_t)blockIdx.x * 64 * 512;
  const short* xb = x2h + (size_t)blockIdx.x * 64 * 512;
  float s = 0.f, q = 0.f;
  for (int c0 = 0; c0 < 512; c0 += 128) {
    for (int qd = tid; qd < 64 * 32; qd += 256) {
      int w_ = qd >> 5, g = qd & 31;
      *(ushort4*)&yt[w_][g * 4] = *(const ushort4*)&yb[(size_t)w_ * 512 + c0 + g * 4];
    }
    __syncthreads();
    for (int cc = part * 32; cc < part * 32 + 32; ++cc) {
      float v = b2f(yt[w][cc]);
      s += v; q += v * v;
    }
    __syncthreads();
  }
  reds[part][w] = s; redq[part][w] = q;
  __syncthreads();
  if (tid < 64) {
    float S = 0.f, Q = 0.f;
    for (int i = 0; i < 4; ++i) { S += reds[i][tid]; Q += redq[i][tid]; }
    float m = S * (1.f / 512.f);
    float var = Q * (1.f / 512.f) - m * m;
    mean_s[tid] = m;
    rstd_s[tid] = rsqrtf(var + 8e-8f);
  }
  __syncthreads();
  float* ob = out + (size_t)b * 512 * 4096 + hh * 64;
  for (int c0 = 0; c0 < 512; c0 += 128) {
    for (int qd = tid; qd < 64 * 32; qd += 256) {
      int w_ = qd >> 5, g = qd & 31;
      *(ushort4*)&yt[w_][g * 4] = *(const ushort4*)&yb[(size_t)w_ * 512 + c0 + g * 4];
      *(ushort4*)&xt2[w_][g * 4] = *(const ushort4*)&xb[(size_t)w_ * 512 + c0 + g * 4];
    }
    __syncthreads();
    for (int it = 0; it < 32; ++it) {
      int c = c0 + it * 4 + part;
      float yv = b2f(yt[w][c - c0]);
      float lnv = (yv - mean_s[w]) * rstd_s[w] * g2[c] + b2p[c];
      float xv = b2f(xt2[w][c - c0]);
      ob[(size_t)c * 4096 + w] = rs2[c] * xv + lnv;
    }
    __syncthreads();
  }
}

extern "C" void kernel_launch(void* const* d_in, const int* in_sizes, int n_in,
                              void* d_out, int out_size, void* d_ws, size_t ws_size,
                              hipStream_t stream) {
  (void)in_sizes; (void)n_in; (void)out_size; (void)ws_size;
  const float* x      = (const float*)d_in[0];
  const float* lpu_w  = (const float*)d_in[1];
  const float* qkv_w  = (const float*)d_in[2];
  const float* out_w  = (const float*)d_in[3];
  const float* cpb_w1 = (const float*)d_in[4];
  const float* cpb_w2 = (const float*)d_in[5];
  const float* lsc    = (const float*)d_in[6];
  const float* g1     = (const float*)d_in[7];
  const float* b1     = (const float*)d_in[8];
  const float* g2     = (const float*)d_in[9];
  const float* b2v    = (const float*)d_in[10];
  const float* pw1_w  = (const float*)d_in[11];
  const float* dw_w   = (const float*)d_in[12];
  const float* pw2_w  = (const float*)d_in[13];
  const float* srs    = (const float*)d_in[14];
  const float* srb    = (const float*)d_in[15];
  const float* rs1    = (const float*)d_in[16];
  const float* rs2    = (const float*)d_in[17];

  char* ws = (char*)d_ws;
  float* btab   = (float*)(ws + 0);
  short* wbq    = (short*)(ws + 16384);
  short* wbo    = (short*)(ws + 1589248);
  short* wb1    = (short*)(ws + 2113536);
  short* wb2    = (short*)(ws + 4210688);
  short* x_temp = (short*)(ws + 8388608);
  short* xw     = (short*)(ws + 75497472);
  short* qkv    = (short*)(ws + 142606336);
  short* o_ws   = (short*)(ws + 343932928);
  short* o4     = (short*)(ws + 75497472);    // = xw (dead)
  short* x2h    = (short*)(ws + 142606336);   // = qkv head (dead); live until k_final
  short* h1     = (short*)(ws + 209715200);   // = qkv tail (dead), 128 MiB
  short* h2     = (short*)(ws + 8388608);     // = x_temp+xw (dead), 128 MiB
  short* yb     = (short*)(ws + 343932928);   // = o_ws (dead)

  k_f2b4<<<3072, 256, 0, stream>>>(qkv_w, wbq, out_w, wbo, pw1_w, wb1, pw2_w, wb2);
  k_cpb<<<225, 64, 0, stream>>>(cpb_w1, cpb_w2, btab);
  k_lpu<<<8192, 256, 0, stream>>>(x, lpu_w, x_temp);
  k_xpose<<<4096, 256, 0, stream>>>(x_temp, xw);
  k_gemm<2><<<6144, 512, 0, stream>>>(xw, wbq, qkv, nullptr, lsc, 1536, 512, 12);
  k_attn<<<1024, 256, 0, stream>>>(qkv, btab, o_ws);
  k_gemm<1><<<2048, 512, 0, stream>>>(o_ws, wbo, nullptr, o4, nullptr, 512, 512, 4);
  k_ln1<<<1024, 256, 0, stream>>>(o4, x_temp, g1, b1, rs1, x2h);
  for (int ch = 0; ch < 2; ++ch) {
    const size_t tok0 = (size_t)ch * 8 * 4096;
    k_gemm<0><<<4096, 512, 0, stream>>>(x2h + tok0 * 512, wb1, h1, nullptr, nullptr, 2048, 512, 16);
    k_dwc2<<<4096, 256, 0, stream>>>(h1, dw_w, srs, srb, h2);
    k_gemm<0><<<1024, 512, 0, stream>>>(h2, wb2, yb + tok0 * 512, nullptr, nullptr, 512, 2048, 4);
  }
  k_final<<<1024, 256, 0, stream>>>(yb, x2h, g2, b2v, rs2, (float*)d_out);
}

// Round 18
// 1083.306 us; speedup vs baseline: 1.0802x; 1.0082x over previous
//
#include <hip/hip_runtime.h>
#include <hip/hip_bf16.h>
#include <stdint.h>

// B=16, C=512, H=W=64, nh=16, hd=32, ws=8, shift=4, N=64 tok/window, Bw=1024,
// hid=2048. Softmax is over the HEAD axis (faithful bug) -> attention mask is
// head-uniform and cancels; logits <= 26 so exp() without max-sub is safe.
// QK row-normalization (+ logits scale on q) is folded into the qkv GEMM
// epilogue (EPI=2). Residual x2 lives only as bf16 NHWC (x2h); no fp32 copy.
//
// Workspace map (bytes), REQUIRES ws_size >= 411,041,792 (392 MiB):
//   [0        ,14400    ) btab f32 [16][225]
//   [16384    ,1589248  ) wbq bf16 [1536][512]
//   [1589248  ,2113536  ) wbo bf16 [512][512]
//   [2113536  ,4210688  ) wb1 bf16 [2048][512]
//   [4210688  ,6307840  ) wb2 bf16 [512][2048]
//   [8388608  ,75497472 ) x_temp bf16 NCHW          (dead after ln1; reused by h2)
//   [75497472 ,142606336) xw bf16 [65536][512]      (dead after qkv gemm; reused by o4, then h2)
//   [142606336,343932928) qkv bf16 [65536][1536]    (dead after attn; head reused by x2h, tail by h1)
//   [343932928,411041792) o_ws bf16 [65536][512]    (dead after out gemm; reused by y)
// x2h stays live until k_final (region [142606336,209715200) untouched after ln1).

typedef float f32x4 __attribute__((ext_vector_type(4)));
typedef short s16x8 __attribute__((ext_vector_type(8)));

__device__ __forceinline__ float b2f(short u) {
  return __uint_as_float(((unsigned)(unsigned short)u) << 16);
}
__device__ __forceinline__ short f2b(float f) {
  __hip_bfloat16 h = __float2bfloat16(f);  // RNE; lowers to v_cvt_pk_bf16_f32
  short s;
  __builtin_memcpy(&s, &h, 2);
  return s;
}
__device__ __forceinline__ void gload16(const void* g, void* l) {
  __builtin_amdgcn_global_load_lds((const unsigned int*)g, (unsigned int*)l, 16, 0, 0);
}

// ---------------- fp32 -> bf16 weight conversion (all 4 weights, one launch) ----------------
__global__ __launch_bounds__(256) void k_f2b4(const float* __restrict__ s0, short* __restrict__ d0,
                                              const float* __restrict__ s1, short* __restrict__ d1,
                                              const float* __restrict__ s2, short* __restrict__ d2,
                                              const float* __restrict__ s3, short* __restrict__ d3) {
  int b = blockIdx.x;
  const float* s;
  short* d;
  int base;
  if (b < 768) { s = s0; d = d0; base = b * 1024; }
  else if (b < 1024) { s = s1; d = d1; base = (b - 768) * 1024; }
  else if (b < 2048) { s = s2; d = d2; base = (b - 1024) * 1024; }
  else { s = s3; d = d3; base = (b - 2048) * 1024; }
  int i = base + threadIdx.x * 4;
  f32x4 v = *(const f32x4*)&s[i];
  ushort4 o;
  o.x = (unsigned short)f2b(v[0]);
  o.y = (unsigned short)f2b(v[1]);
  o.z = (unsigned short)f2b(v[2]);
  o.w = (unsigned short)f2b(v[3]);
  *(ushort4*)&d[i] = o;
}

// ---------------- CPB bias table: btab[h][rpi] = 16*sigmoid(mlp(table[rpi])) ----------------
__global__ __launch_bounds__(64) void k_cpb(const float* __restrict__ w1,
                                            const float* __restrict__ w2,
                                            float* __restrict__ btab) {
  const int r = blockIdx.x;      // 0..224
  const int lane = threadIdx.x;  // 0..63
  const int ri = r / 15, rj = r % 15;
  float th = (float)(ri - 7) * (8.f / 7.f);
  float tw = (float)(rj - 7) * (8.f / 7.f);
  float gh = copysignf(log2f(fabsf(th) + 1.f) * (1.f / 3.f), th);
  float gw = copysignf(log2f(fabsf(tw) + 1.f) * (1.f / 3.f), tw);
  const int h = lane >> 2, pp = lane & 3;
  float acc = 0.f;
  for (int k = 0; k < 128; ++k) {
    int hh = pp * 128 + k;
    float a = gh * w1[hh * 2] + gw * w1[hh * 2 + 1];
    float r6 = fminf(fmaxf(a + 3.f, 0.f), 6.f);
    float hsw = a * r6 * (1.f / 6.f);
    acc += hsw * w2[h * 512 + hh];
  }
  acc += __shfl_xor(acc, 1);
  acc += __shfl_xor(acc, 2);
  if ((lane & 3) == 0) btab[h * 225 + r] = 16.f / (1.f + __expf(-acc));
}

// ---------------- LPU: x + depthwise 3x3 (SAME), out bf16 NCHW ----------------
__global__ __launch_bounds__(256) void k_lpu(const float* __restrict__ x,
                                             const float* __restrict__ lw,
                                             short* __restrict__ xt) {
  __shared__ float img[64 * 68];
  const int bc = blockIdx.x;  // b*512+c
  const int c = bc & 511;
  const float* img_g = x + (size_t)bc * 4096;
  short* outp = xt + (size_t)bc * 4096;
  const int tid = threadIdx.x;
#pragma unroll
  for (int t = 0; t < 4; ++t) {
    int idx = t * 256 + tid;
    int h = idx >> 4, w4 = (idx & 15) * 4;
    f32x4 v = *(const f32x4*)&img_g[h * 64 + w4];
    *(f32x4*)&img[h * 68 + w4] = v;
  }
  float wreg[9];
#pragma unroll
  for (int t = 0; t < 9; ++t) wreg[t] = lw[c * 9 + t];
  __syncthreads();
  const int hb = tid >> 4, w0 = (tid & 15) * 4;
#pragma unroll
  for (int g = 0; g < 4; ++g) {
    int h = hb + g * 16;
    float row[3][6];
#pragma unroll
    for (int dr = 0; dr < 3; ++dr) {
      int hh = h - 1 + dr;
      if (hh < 0 || hh > 63) {
#pragma unroll
        for (int j = 0; j < 6; ++j) row[dr][j] = 0.f;
      } else {
        f32x4 m = *(const f32x4*)&img[hh * 68 + w0];
        row[dr][1] = m[0]; row[dr][2] = m[1]; row[dr][3] = m[2]; row[dr][4] = m[3];
        row[dr][0] = (w0 > 0) ? img[hh * 68 + w0 - 1] : 0.f;
        row[dr][5] = (w0 < 60) ? img[hh * 68 + w0 + 4] : 0.f;
      }
    }
    ushort4 o;
    unsigned short op[4];
#pragma unroll
    for (int p = 0; p < 4; ++p) {
      float acc = row[1][p + 1];
#pragma unroll
      for (int dr = 0; dr < 3; ++dr)
#pragma unroll
        for (int dc = 0; dc < 3; ++dc)
          acc += wreg[dr * 3 + dc] * row[dr][p + dc];
      op[p] = (unsigned short)f2b(acc);
    }
    o.x = op[0]; o.y = op[1]; o.z = op[2]; o.w = op[3];
    *(ushort4*)&outp[h * 64 + w0] = o;
  }
}

// ---------------- roll(-4,-4) over (tokens,channels) + window partition ----------------
__global__ __launch_bounds__(256) void k_xpose(const short* __restrict__ xt,
                                               short* __restrict__ xw) {
  __shared__ short tile[64][132];
  const int tid = threadIdx.x;
  const int cq = blockIdx.x & 3;
  const int h = (blockIdx.x >> 2) & 63;
  const int b = blockIdx.x >> 8;
  const int c0 = cq * 128;
#pragma unroll
  for (int t = 0; t < 4; ++t) {
    int u = t * 256 + tid;            // 0..1023 = 128 cc x 8 ww-octets
    int ww0 = (u & 7) * 8, cc = u >> 3;
    int csrc = (c0 + cc + 4) & 511;
    s16x8 v = *(const s16x8*)&xt[(((size_t)b * 512 + csrc) * 64 + h) * 64 + ww0];
#pragma unroll
    for (int j = 0; j < 8; ++j) tile[ww0 + j][cc] = v[j];
  }
  __syncthreads();
  for (int qd = tid; qd < 64 * 32; qd += 256) {
    int ws_ = qd >> 5, cqq = qd & 31, cc = cqq * 4;
    int t = (h * 64 + ws_ + 4092) & 4095;
    int hd = t >> 6, wd = t & 63;
    int tok = (b * 64 + (hd >> 3) * 8 + (wd >> 3)) * 64 + (hd & 7) * 8 + (wd & 7);
    ushort4 u = *(const ushort4*)&tile[ws_][cc];
    *(ushort4*)&xw[(size_t)tok * 512 + c0 + cc] = u;
  }
}

// ---------------- 128x128 bf16 GEMM v6: dbuf stage-early + counted vmcnt + 1-phase epilogue ----------------
// 8 waves (2M x 4N, 64x32/wave); raw s_barrier with vmcnt(4). T2 both-sides swizzle;
// T5 setprio. Epilogue: full-tile ct[128][136] (34.8 KB in smem), all waves write,
// ONE barrier, ushort8 stores. EPI 0: bf16 C. EPI 1: scatter o4. EPI 2: q/k norm.
template <int EPI>
__global__ __launch_bounds__(512) void k_gemm(const short* __restrict__ A,
                                              const short* __restrict__ B,
                                              short* __restrict__ C,
                                              short* __restrict__ o4,
                                              const float* __restrict__ lsc,
                                              int N, int K, int gx) {
  __shared__ short smem[2 * 16384];  // buf b: A at b*16384, B at +8192 (64 KiB)
  const int nwg = gridDim.x;
  const int orig = blockIdx.x;
  const int wgid = (orig & 7) * (nwg >> 3) + (orig >> 3);
  const int bx = wgid % gx, by = wgid / gx;
  const int tid = threadIdx.x;
  const int lane = tid & 63, wid = tid >> 6;  // 8 waves
  const int wm = wid >> 2, wn = wid & 3;      // 2M x 4N
  const int m0 = by * 128, n0 = bx * 128;
  const f32x4 fz = {0.f, 0.f, 0.f, 0.f};
  f32x4 acc[4][2];
#pragma unroll
  for (int m = 0; m < 4; ++m) { acc[m][0] = fz; acc[m][1] = fz; }
  const int rst = lane >> 3;
  const int cst = ((lane & 7) ^ rst) * 8;  // pre-swizzled source column slot
  const int l15 = lane & 15, l4 = lane >> 4, l7 = lane & 7;
  const short* ag[2];
  const short* bg[2];
#pragma unroll
  for (int l = 0; l < 2; ++l) {
    int h8 = wid * 2 + l;  // 0..15 -> rows h8*8+rst
    ag[l] = A + (size_t)(m0 + h8 * 8 + rst) * K + cst;
    bg[l] = B + (size_t)(n0 + h8 * 8 + rst) * K + cst;
  }
  const int nt = K >> 6;
  auto STAGE = [&](int b) {  // 4 gload_lds per thread
    short* as = smem + b * 16384;
    short* bs = as + 8192;
#pragma unroll
    for (int l = 0; l < 2; ++l) {
      int h8 = wid * 2 + l;
      gload16(ag[l], as + h8 * 512);
      gload16(bg[l], bs + h8 * 512);
      ag[l] += 64;
      bg[l] += 64;
    }
  };
  STAGE(0);
  for (int kt = 0; kt < nt; ++kt) {
    const int cur = kt & 1;
    if (kt + 1 < nt) {
      STAGE(cur ^ 1);  // 4 more loads in flight
      asm volatile("s_waitcnt vmcnt(4)" ::: "memory");  // oldest 4 (buf[cur]) done
    } else {
      asm volatile("s_waitcnt vmcnt(0)" ::: "memory");
    }
    __builtin_amdgcn_s_barrier();            // all waves: buf[cur] ready
    __builtin_amdgcn_sched_barrier(0);       // pin ds_reads below the barrier
    const short* as = smem + cur * 16384;
    const short* bs = as + 8192;
    __builtin_amdgcn_s_setprio(1);
#pragma unroll
    for (int ks = 0; ks < 2; ++ks) {
      s16x8 af[4], bfr[2];
#pragma unroll
      for (int m = 0; m < 4; ++m)
        af[m] = *(const s16x8*)&as[(wm * 64 + m * 16 + l15) * 64 + (((ks * 4 + l4) ^ l7) * 8)];
#pragma unroll
      for (int n = 0; n < 2; ++n)
        bfr[n] = *(const s16x8*)&bs[(wn * 32 + n * 16 + l15) * 64 + (((ks * 4 + l4) ^ l7) * 8)];
#pragma unroll
      for (int m = 0; m < 4; ++m)
#pragma unroll
        for (int n = 0; n < 2; ++n)
          acc[m][n] = __builtin_amdgcn_mfma_f32_16x16x32_bf16(af[m], bfr[n],
                                                              acc[m][n], 0, 0, 0);
    }
    __builtin_amdgcn_s_setprio(0);
    __builtin_amdgcn_sched_barrier(0);       // keep reads above the barrier
    __builtin_amdgcn_s_barrier();            // all waves done reading buf[cur]
    __builtin_amdgcn_sched_barrier(0);       // pin next STAGE below the barrier
  }
  if (EPI == 2) {
    const int cb = n0 + wn * 32;  // this wave's 32-col head band
    if (cb < 1024) {
      float sc = 1.f;
      if (cb < 512) sc = __expf(fminf(lsc[cb >> 5], 4.605170185988092f));
#pragma unroll
      for (int m = 0; m < 4; ++m)
#pragma unroll
        for (int r = 0; r < 4; ++r) {
          float s0 = acc[m][0][r], s1 = acc[m][1][r];
          float ss = s0 * s0 + s1 * s1;
          ss += __shfl_xor(ss, 1);
          ss += __shfl_xor(ss, 2);
          ss += __shfl_xor(ss, 4);
          ss += __shfl_xor(ss, 8);
          float mul = sc / fmaxf(sqrtf(ss), 1e-12f);
          acc[m][0][r] = s0 * mul;
          acc[m][1][r] = s1 * mul;
        }
    }
  }
  // ---- epilogue v2: single phase, full-tile ct[128][136], 1 barrier ----
  // K-loop's final s_barrier already separates last LDS reads from these writes.
  short* ct = smem;  // 34816 B < 64 KiB smem
#pragma unroll
  for (int m = 0; m < 4; ++m)
#pragma unroll
    for (int n = 0; n < 2; ++n)
#pragma unroll
      for (int r = 0; r < 4; ++r) {
        int lr = wm * 64 + m * 16 + l4 * 4 + r;
        int lc = wn * 32 + n * 16 + l15;
        ct[lr * 136 + lc] = f2b(acc[m][n][r]);
      }
  __syncthreads();
#pragma unroll
  for (int u = 0; u < 4; ++u) {
    int unit = u * 512 + tid;          // 0..2047 = 128 rows x 16 slots
    int lr = unit >> 4, cs = unit & 15;
    s16x8 v = *(const s16x8*)&ct[lr * 136 + cs * 8];
    int grow = m0 + lr;
    int gcol = n0 + cs * 8;
    if (EPI != 1) {
      *(s16x8*)&C[(size_t)grow * N + gcol] = v;
    } else {
      int win = grow >> 6, nn = grow & 63;
      int b = win >> 6, whs = (win >> 3) & 7, wws = win & 7;
      int ih = nn >> 3, iw = nn & 7;
      int wh = (whs + 4) & 7, ww = (wws + 4) & 7;
      int cp = ww * 64 + wh * 8 + ih;
      int hp = iw * 8 + (gcol >> 6);
      int wp = gcol & 63;
      *(s16x8*)&o4[(((size_t)b * 512 + cp) * 64 + hp) * 64 + wp] = v;
    }
  }
}

// ---------------- fused attention v3: pre-normalized q,k; wave owns 16 rows x all heads ----------------
__global__ __launch_bounds__(256) void k_attn(const short* __restrict__ qkv,
                                              const float* __restrict__ btab_g,
                                              short* __restrict__ o_ws) {
  __shared__ float btab[3600];      // [h][225]
  __shared__ short vts[2][2048];    // V^T[32][64] swizzled, double-buffered
  __shared__ short pts[4][1024];    // per-wave P[16][64] swizzled
  const int tid = threadIdx.x, lane = tid & 63, wid = tid >> 6;
  const int win = blockIdx.x;
  const int l15 = lane & 15, l4 = lane >> 4;
  const int qrow0 = wid * 16;
  for (int i = tid; i < 3600; i += 256) btab[i] = btab_g[i];
  int baddr[4][4];
#pragma unroll
  for (int n = 0; n < 4; ++n)
#pragma unroll
    for (int r = 0; r < 4; ++r) {
      int i_ = qrow0 + l4 * 4 + r, j_ = n * 16 + l15;
      int dih = (i_ >> 3) - (j_ >> 3) + 7;
      int diw = (i_ & 7) - (j_ & 7) + 7;
      baddr[n][r] = dih * 15 + diw;
    }
  __syncthreads();
  const short* base = qkv + (size_t)win * 64 * 1536;
  const f32x4 fz = {0.f, 0.f, 0.f, 0.f};
  f32x4 sump[4] = {fz, fz, fz, fz};
#pragma unroll 2
  for (int h = 0; h < 16; ++h) {
    s16x8 qf = *(const s16x8*)(base + (size_t)(qrow0 + l15) * 1536 + h * 32 + l4 * 8);
#pragma unroll
    for (int n = 0; n < 4; ++n) {
      s16x8 kf = *(const s16x8*)(base + (size_t)(n * 16 + l15) * 1536 + 512 + h * 32 + l4 * 8);
      f32x4 s = __builtin_amdgcn_mfma_f32_16x16x32_bf16(qf, kf, fz, 0, 0, 0);
#pragma unroll
      for (int r = 0; r < 4; ++r)
        sump[n][r] += __expf(s[r] + btab[h * 225 + baddr[n][r]]);
    }
  }
  f32x4 rden[4];
#pragma unroll
  for (int n = 0; n < 4; ++n)
#pragma unroll
    for (int r = 0; r < 4; ++r) rden[n][r] = 1.f / sump[n][r];
  char* pt = (char*)pts[wid];
  {
    int j = tid & 63, d0 = (tid >> 6) * 8;
    s16x8 vv = *(const s16x8*)(base + (size_t)j * 1536 + 1024 + d0);
#pragma unroll
    for (int jj = 0; jj < 8; ++jj) {
      int d = d0 + jj;
      *(short*)((char*)vts[0] + ((d * 128 + j * 2) ^ ((d & 7) << 4))) = vv[jj];
    }
  }
  __syncthreads();
  for (int h = 0; h < 16; ++h) {
    const char* vcur = (const char*)vts[h & 1];
    if (h < 15) {
      int j = tid & 63, d0 = (tid >> 6) * 8;
      s16x8 vv = *(const s16x8*)(base + (size_t)j * 1536 + 1024 + (h + 1) * 32 + d0);
      char* vnxt = (char*)vts[(h + 1) & 1];
#pragma unroll
      for (int jj = 0; jj < 8; ++jj) {
        int d = d0 + jj;
        *(short*)(vnxt + ((d * 128 + j * 2) ^ ((d & 7) << 4))) = vv[jj];
      }
    }
    s16x8 qf = *(const s16x8*)(base + (size_t)(qrow0 + l15) * 1536 + h * 32 + l4 * 8);
#pragma unroll
    for (int n = 0; n < 4; ++n) {
      s16x8 kf = *(const s16x8*)(base + (size_t)(n * 16 + l15) * 1536 + 512 + h * 32 + l4 * 8);
      f32x4 s = __builtin_amdgcn_mfma_f32_16x16x32_bf16(qf, kf, fz, 0, 0, 0);
#pragma unroll
      for (int r = 0; r < 4; ++r) {
        float pv = __expf(s[r] + btab[h * 225 + baddr[n][r]]) * rden[n][r];
        int i_loc = l4 * 4 + r, j_ = n * 16 + l15;
        *(short*)(pt + ((i_loc * 128 + j_ * 2) ^ ((i_loc & 7) << 4))) = f2b(pv);
      }
    }
    f32x4 oacc[2] = {fz, fz};
#pragma unroll
    for (int kb = 0; kb < 2; ++kb) {
      s16x8 af = *(const s16x8*)(pt + ((l15 * 128 + kb * 64 + l4 * 16) ^ ((l15 & 7) << 4)));
#pragma unroll
      for (int db = 0; db < 2; ++db) {
        int d = db * 16 + l15;
        s16x8 bf = *(const s16x8*)(vcur + ((d * 128 + kb * 64 + l4 * 16) ^ ((d & 7) << 4)));
        oacc[db] = __builtin_amdgcn_mfma_f32_16x16x32_bf16(af, bf, oacc[db], 0, 0, 0);
      }
    }
    short* ob = o_ws + ((size_t)win * 64 + qrow0) * 512 + h * 32;
#pragma unroll
    for (int db = 0; db < 2; ++db)
#pragma unroll
      for (int r = 0; r < 4; ++r)
        ob[(size_t)(l4 * 4 + r) * 512 + db * 16 + l15] = f2b(oacc[db][r]);
    __syncthreads();
  }
}

// ---------------- LN1 over channels of o4 + residual rs1*x_temp -> x2h (bf16 NHWC only) ----------------
__global__ __launch_bounds__(256) void k_ln1(const short* __restrict__ o4,
                                             const short* __restrict__ xt,
                                             const float* __restrict__ g1,
                                             const float* __restrict__ b1,
                                             const float* __restrict__ rs1,
                                             short* __restrict__ x2h) {
  __shared__ float reds[4][64], redq[4][64];
  __shared__ float mean_s[64], rstd_s[64];
  __shared__ short tile[128][66];
  const int tid = threadIdx.x;
  const int b = blockIdx.x >> 6, hp = blockIdx.x & 63;
  const int w = tid & 63, part = tid >> 6;
  const short* base = o4 + (size_t)b * 512 * 4096 + hp * 64;
  float s = 0.f, q = 0.f;
  for (int c = part; c < 512; c += 4) {
    float v = b2f(base[(size_t)c * 4096 + w]);
    s += v; q += v * v;
  }
  reds[part][w] = s; redq[part][w] = q;
  __syncthreads();
  if (tid < 64) {
    float S = 0.f, Q = 0.f;
    for (int i = 0; i < 4; ++i) { S += reds[i][tid]; Q += redq[i][tid]; }
    float m = S * (1.f / 512.f);
    float var = Q * (1.f / 512.f) - m * m;
    mean_s[tid] = m;
    rstd_s[tid] = rsqrtf(var + 8e-8f);
  }
  __syncthreads();
  const short* xtb = xt + (size_t)b * 512 * 4096 + hp * 64;
  for (int c0 = 0; c0 < 512; c0 += 128) {
    for (int cc = part; cc < 128; cc += 4) {
      int c = c0 + cc;
      float v = b2f(base[(size_t)c * 4096 + w]);
      float ln = (v - mean_s[w]) * rstd_s[w] * g1[c] + b1[c];
      float xv = rs1[c] * b2f(xtb[(size_t)c * 4096 + w]) + ln;
      tile[cc][w] = f2b(xv);
    }
    __syncthreads();
    short* xh = x2h + ((size_t)blockIdx.x * 64) * 512 + c0;
    for (int qd = tid; qd < 64 * 32; qd += 256) {
      int w_ = qd >> 5, cq = qd & 31, cc = cq * 4;
      ushort4 u;
      u.x = (unsigned short)tile[cc][w_];
      u.y = (unsigned short)tile[cc + 1][w_];
      u.z = (unsigned short)tile[cc + 2][w_];
      u.w = (unsigned short)tile[cc + 3][w_];
      *(ushort4*)&xh[(size_t)w_ * 512 + cc] = u;
    }
    __syncthreads();
  }
}

// ---------------- depthwise 3x3 on h1 (2048ch NHWC bf16, 8-image chunk) + StarReLU ----------------
__global__ __launch_bounds__(256) void k_dwc2(const short* __restrict__ h1,
                                              const float* __restrict__ dw,
                                              const float* __restrict__ srs_p,
                                              const float* __restrict__ srb_p,
                                              short* __restrict__ h2) {
  __shared__ short tile[6 * 64 * 64];  // [row][w][cg^(w&7)][8]
  const int tid = threadIdx.x;
  const int cblk = blockIdx.x & 31;
  const int hq = (blockIdx.x >> 5) & 15;
  const int b = blockIdx.x >> 9;
  const int c0 = cblk * 64;
  const int h0 = hq * 4;
  for (int t = 0; t < 12; ++t) {
    int idx = t * 256 + tid;
    int cg = idx & 7;
    int wl = (idx >> 3) & 63;
    int rl = idx >> 9;
    int hr = h0 - 1 + rl;
    s16x8 v = {0, 0, 0, 0, 0, 0, 0, 0};
    if (hr >= 0 && hr < 64)
      v = *(const s16x8*)&h1[((size_t)b * 4096 + hr * 64 + wl) * 2048 + c0 + cg * 8];
    *(s16x8*)&tile[(rl * 64 + wl) * 64 + (cg ^ (wl & 7)) * 8] = v;
  }
  const int cg = tid & 7;
  const int wq = tid >> 3;
  float wt[9][8];
#pragma unroll
  for (int j = 0; j < 8; ++j) {
    int cch = c0 + cg * 8 + j;
#pragma unroll
    for (int t = 0; t < 9; ++t) wt[t][j] = dw[cch * 9 + t];
  }
  const float srs = *srs_p, srb = *srb_p;
  __syncthreads();
#pragma unroll
  for (int it = 0; it < 8; ++it) {
    int wl = wq + (it & 1) * 32;
    int rl = it >> 1;
    s16x8 ctr = *(const s16x8*)&tile[((rl + 1) * 64 + wl) * 64 + (cg ^ (wl & 7)) * 8];
    float acc[8];
#pragma unroll
    for (int j = 0; j < 8; ++j) acc[j] = b2f(ctr[j]);
#pragma unroll
    for (int dh = -1; dh <= 1; ++dh) {
      int row = rl + 1 + dh;
#pragma unroll
      for (int dwi = -1; dwi <= 1; ++dwi) {
        int wn = wl + dwi;
        if (wn < 0 || wn > 63) continue;
        s16x8 v = *(const s16x8*)&tile[(row * 64 + wn) * 64 + (cg ^ (wn & 7)) * 8];
        const float* wrow = wt[(dh + 1) * 3 + dwi + 1];
#pragma unroll
        for (int j = 0; j < 8; ++j) acc[j] += wrow[j] * b2f(v[j]);
      }
    }
    s16x8 o;
#pragma unroll
    for (int j = 0; j < 8; ++j) {
      float rr = fmaxf(acc[j], 0.f);
      o[j] = f2b(srs * rr * rr + srb);
    }
    *(s16x8*)&h2[((size_t)b * 4096 + (h0 + rl) * 64 + wl) * 2048 + c0 + cg * 8] = o;
  }
}

// ---------------- final: out = rs2*x2h + LN_c(y), NCHW f32 output ----------------
__global__ __launch_bounds__(256) void k_final(const short* __restrict__ y,
                                               const short* __restrict__ x2h,
                                               const float* __restrict__ g2,
                                               const float* __restrict__ b2p,
                                               const float* __restrict__ rs2,
                                               float* __restrict__ out) {
  __shared__ short yt[64][132];
  __shared__ short xt2[64][132];
  __shared__ float reds[4][64], redq[4][64];
  __shared__ float mean_s[64], rstd_s[64];
  const int tid = threadIdx.x;
  const int b = blockIdx.x >> 6, hh = blockIdx.x & 63;
  const int w = tid & 63, part = tid >> 6;
  const short* yb = y + (size_t)blockIdx.x * 64 * 512;
  const short* xb = x2h + (size_t)blockIdx.x * 64 * 512;
  float s = 0.f, q = 0.f;
  for (int c0 = 0; c0 < 512; c0 += 128) {
    for (int qd = tid; qd < 64 * 32; qd += 256) {
      int w_ = qd >> 5, g = qd & 31;
      *(ushort4*)&yt[w_][g * 4] = *(const ushort4*)&yb[(size_t)w_ * 512 + c0 + g * 4];
    }
    __syncthreads();
    for (int cc = part * 32; cc < part * 32 + 32; ++cc) {
      float v = b2f(yt[w][cc]);
      s += v; q += v * v;
    }
    __syncthreads();
  }
  reds[part][w] = s; redq[part][w] = q;
  __syncthreads();
  if (tid < 64) {
    float S = 0.f, Q = 0.f;
    for (int i = 0; i < 4; ++i) { S += reds[i][tid]; Q += redq[i][tid]; }
    float m = S * (1.f / 512.f);
    float var = Q * (1.f / 512.f) - m * m;
    mean_s[tid] = m;
    rstd_s[tid] = rsqrtf(var + 8e-8f);
  }
  __syncthreads();
  float* ob = out + (size_t)b * 512 * 4096 + hh * 64;
  for (int c0 = 0; c0 < 512; c0 += 128) {
    for (int qd = tid; qd < 64 * 32; qd += 256) {
      int w_ = qd >> 5, g = qd & 31;
      *(ushort4*)&yt[w_][g * 4] = *(const ushort4*)&yb[(size_t)w_ * 512 + c0 + g * 4];
      *(ushort4*)&xt2[w_][g * 4] = *(const ushort4*)&xb[(size_t)w_ * 512 + c0 + g * 4];
    }
    __syncthreads();
    for (int it = 0; it < 32; ++it) {
      int c = c0 + it * 4 + part;
      float yv = b2f(yt[w][c - c0]);
      float lnv = (yv - mean_s[w]) * rstd_s[w] * g2[c] + b2p[c];
      float xv = b2f(xt2[w][c - c0]);
      ob[(size_t)c * 4096 + w] = rs2[c] * xv + lnv;
    }
    __syncthreads();
  }
}

extern "C" void kernel_launch(void* const* d_in, const int* in_sizes, int n_in,
                              void* d_out, int out_size, void* d_ws, size_t ws_size,
                              hipStream_t stream) {
  (void)in_sizes; (void)n_in; (void)out_size; (void)ws_size;
  const float* x      = (const float*)d_in[0];
  const float* lpu_w  = (const float*)d_in[1];
  const float* qkv_w  = (const float*)d_in[2];
  const float* out_w  = (const float*)d_in[3];
  const float* cpb_w1 = (const float*)d_in[4];
  const float* cpb_w2 = (const float*)d_in[5];
  const float* lsc    = (const float*)d_in[6];
  const float* g1     = (const float*)d_in[7];
  const float* b1     = (const float*)d_in[8];
  const float* g2     = (const float*)d_in[9];
  const float* b2v    = (const float*)d_in[10];
  const float* pw1_w  = (const float*)d_in[11];
  const float* dw_w   = (const float*)d_in[12];
  const float* pw2_w  = (const float*)d_in[13];
  const float* srs    = (const float*)d_in[14];
  const float* srb    = (const float*)d_in[15];
  const float* rs1    = (const float*)d_in[16];
  const float* rs2    = (const float*)d_in[17];

  char* ws = (char*)d_ws;
  float* btab   = (float*)(ws + 0);
  short* wbq    = (short*)(ws + 16384);
  short* wbo    = (short*)(ws + 1589248);
  short* wb1    = (short*)(ws + 2113536);
  short* wb2    = (short*)(ws + 4210688);
  short* x_temp = (short*)(ws + 8388608);
  short* xw     = (short*)(ws + 75497472);
  short* qkv    = (short*)(ws + 142606336);
  short* o_ws   = (short*)(ws + 343932928);
  short* o4     = (short*)(ws + 75497472);    // = xw (dead)
  short* x2h    = (short*)(ws + 142606336);   // = qkv head (dead); live until k_final
  short* h1     = (short*)(ws + 209715200);   // = qkv tail (dead), 128 MiB
  short* h2     = (short*)(ws + 8388608);     // = x_temp+xw (dead), 128 MiB
  short* yb     = (short*)(ws + 343932928);   // = o_ws (dead)

  k_f2b4<<<3072, 256, 0, stream>>>(qkv_w, wbq, out_w, wbo, pw1_w, wb1, pw2_w, wb2);
  k_cpb<<<225, 64, 0, stream>>>(cpb_w1, cpb_w2, btab);
  k_lpu<<<8192, 256, 0, stream>>>(x, lpu_w, x_temp);
  k_xpose<<<4096, 256, 0, stream>>>(x_temp, xw);
  k_gemm<2><<<6144, 512, 0, stream>>>(xw, wbq, qkv, nullptr, lsc, 1536, 512, 12);
  k_attn<<<1024, 256, 0, stream>>>(qkv, btab, o_ws);
  k_gemm<1><<<2048, 512, 0, stream>>>(o_ws, wbo, nullptr, o4, nullptr, 512, 512, 4);
  k_ln1<<<1024, 256, 0, stream>>>(o4, x_temp, g1, b1, rs1, x2h);
  for (int ch = 0; ch < 2; ++ch) {
    const size_t tok0 = (size_t)ch * 8 * 4096;
    k_gemm<0><<<4096, 512, 0, stream>>>(x2h + tok0 * 512, wb1, h1, nullptr, nullptr, 2048, 512, 16);
    k_dwc2<<<4096, 256, 0, stream>>>(h1, dw_w, srs, srb, h2);
    k_gemm<0><<<1024, 512, 0, stream>>>(h2, wb2, yb + tok0 * 512, nullptr, nullptr, 512, 2048, 4);
  }
  k_final<<<1024, 256, 0, stream>>>(yb, x2h, g2, b2v, rs2, (float*)d_out);
}